// Round 7
// baseline (554.681 us; speedup 1.0000x reference)
//
#include <hip/hip_runtime.h>
#include <hip/hip_bf16.h>

// MolecularGraphNet: 3x SAGEConv(mean) + Linear, on MI355X.
//  - All activations live in chunk-linear swizzled format:
//      elem(r,k) of [rows,K] at (r>>7)*(K*128) + (k>>3)*1024 + (r&127)*8 + (k&7)
//    GEMM stages contiguous 16 KB blocks; aggregation gathers a node's
//    8-feat group as one contiguous uint4. No row-major copies anywhere.
//  - GEMM: 128x128 tile, BK=64, global_load_lds(16B), XCD-aware remap.
//  - Aggregation: XCD-sliced (slice->fixed XCD, ~2.6 MB/XCD in L2) with
//    16 edges in flight per wave (lane = edge j x 16B chunk c), shfl reduce.

typedef __bf16 bf16x8 __attribute__((ext_vector_type(8)));
typedef float  f32x4  __attribute__((ext_vector_type(4)));

#define N_NODES 20000
#define N_EDGES 320000
#define MPAD 20096   // 157*128

__device__ __forceinline__ int clampi(int v, int lo, int hi) {
    return v < lo ? lo : (v > hi ? hi : v);
}

__device__ __forceinline__ void load16_lds(const void* g, void* l) {
    __builtin_amdgcn_global_load_lds(
        (const __attribute__((address_space(1))) void*)g,
        (__attribute__((address_space(3))) void*)l, 16, 0, 0);
}

// ---------------- CSR build ----------------

__global__ void k_count(const int* __restrict__ ei, int E, int* __restrict__ cnt) {
    int e = blockIdx.x * blockDim.x + threadIdx.x;
    if (e < E) atomicAdd(&cnt[clampi(ei[E + e], 0, N_NODES - 1)], 1);
}

__global__ __launch_bounds__(1024) void k_scan_block(const int* __restrict__ cnt,
                                                     int* __restrict__ off,
                                                     int* __restrict__ bsum, int n) {
    __shared__ int sm[1024];
    int b = blockIdx.x, tid = threadIdx.x;
    int i = b * 1024 + tid;
    int v = (i < n) ? cnt[i] : 0;
    sm[tid] = v;
    __syncthreads();
    for (int s = 1; s < 1024; s <<= 1) {
        int t = (tid >= s) ? sm[tid - s] : 0;
        __syncthreads();
        sm[tid] += t;
        __syncthreads();
    }
    if (i < n) off[i] = sm[tid] - v;
    if (tid == 1023) bsum[b] = sm[1023];
}

__global__ void k_scan_carry(const int* __restrict__ bsum, int* __restrict__ carry,
                             int nb, int* __restrict__ off, int n) {
    if (threadIdx.x == 0 && blockIdx.x == 0) {
        int acc = 0;
        for (int b = 0; b < nb; ++b) { carry[b] = acc; acc += bsum[b]; }
        off[n] = acc;
    }
}

__global__ __launch_bounds__(1024) void k_scan_add(int* __restrict__ off,
                                                   int* __restrict__ cur,
                                                   const int* __restrict__ carry, int n) {
    int i = blockIdx.x * 1024 + threadIdx.x;
    if (i < n) {
        int v = off[i] + carry[blockIdx.x];
        off[i] = v;
        cur[i] = v;
    }
}

__global__ void k_fill(const int* __restrict__ ei, int E,
                       int* __restrict__ cur, int* __restrict__ csr) {
    int e = blockIdx.x * blockDim.x + threadIdx.x;
    if (e < E) {
        int dst = clampi(ei[E + e], 0, N_NODES - 1);
        int src = clampi(ei[e], 0, N_NODES - 1);
        int pos = atomicAdd(&cur[dst], 1);
        if (pos >= 0 && pos < E) csr[pos] = src;
    }
}

// ---------------- fused weight transposes: W fp32 [K,N] -> swizzled bf16 [N,KT] ----------------

struct TDesc { const float* W; __bf16* Wt; int K, N, KT, koff, tile0; };
struct TDescs { TDesc d[7]; };

__global__ void k_transpose_all(TDescs ds) {
    __shared__ float tile[32][33];
    int b = blockIdx.x;
    int di = 0;
#pragma unroll
    for (int i = 1; i < 7; ++i)
        if (b >= ds.d[i].tile0) di = i;
    const float* W = ds.d[di].W;
    __bf16* Wt = ds.d[di].Wt;
    int N = ds.d[di].N, KT = ds.d[di].KT, koff = ds.d[di].koff;
    int t = b - ds.d[di].tile0;
    int ntn = N >> 5;
    int nb = (t % ntn) * 32, kb = (t / ntn) * 32;
    for (int i = 0; i < 32; i += 8) {
        int k = kb + threadIdx.y + i, n = nb + threadIdx.x;
        tile[threadIdx.y + i][threadIdx.x] = W[(size_t)k * N + n];
    }
    __syncthreads();
    for (int i = 0; i < 32; i += 8) {
        int n = nb + threadIdx.y + i, k = koff + kb + threadIdx.x;
        size_t o = (size_t)(n >> 7) * ((size_t)KT * 128) + (size_t)(k >> 3) * 1024 +
                   (size_t)((n & 127) * 8) + (k & 7);
        Wt[o] = (__bf16)tile[threadIdx.x][threadIdx.y + i];
    }
}

// ---------------- x fp32 -> swizzled bf16 (right half of Acat1) ----------------
// grid (157, 16), block 256: chunk = by*2 + (tid>>7), node_l = tid&127.

__global__ __launch_bounds__(256) void k_convx(const float* __restrict__ x,
                                               __bf16* __restrict__ acat) {
    int tile = blockIdx.x;
    int chunk = blockIdx.y * 2 + (threadIdx.x >> 7);
    int nl = threadIdx.x & 127;
    int node = tile * 128 + nl;
    __bf16 tmp[8] = {};
    if (node < N_NODES) {
        float4 u = *(const float4*)(x + (size_t)node * 256 + chunk * 8);
        float4 w = *(const float4*)(x + (size_t)node * 256 + chunk * 8 + 4);
        tmp[0] = (__bf16)u.x; tmp[1] = (__bf16)u.y; tmp[2] = (__bf16)u.z; tmp[3] = (__bf16)u.w;
        tmp[4] = (__bf16)w.x; tmp[5] = (__bf16)w.y; tmp[6] = (__bf16)w.z; tmp[7] = (__bf16)w.w;
    }
    *(uint4*)(acat + (size_t)tile * (512 * 128) + (size_t)(32 + chunk) * 1024 +
              (size_t)(nl * 8)) = *(const uint4*)tmp;
}

// ---------------- XCD-sliced aggregation (CSR gather, mean), swizzled I/O ----------------
// Wave = one node. lane = (edge j = lane>>2) x (16B chunk c = lane&3): 16 edges
// in flight per iteration. Reduce over j via shfl_xor(4,8,16,32).

// layer 1: gathers Acat1 h-half (chunks 32..63, 256 bf16 feats), 8 slices x 32 feats.
__global__ __launch_bounds__(256) void k_agg1(const int* __restrict__ off,
                                              const int* __restrict__ csr,
                                              __bf16* __restrict__ acat) {
    int bid = blockIdx.x;
    int slice = bid & 7, group = bid >> 3;
    int wave = threadIdx.x >> 6, lane = threadIdx.x & 63;
    int node = group * 4 + wave;
    int j = lane >> 2, c = lane & 3;
    int beg = off[node], end = off[node + 1];
    const __bf16* src = acat + (size_t)(32 + slice * 4 + c) * 1024;
    float a[8] = {};
    for (int e = beg + j; e < end; e += 16) {
        int s = csr[e];
        uint4 v = *(const uint4*)(src + (size_t)(s >> 7) * (512 * 128) + (size_t)((s & 127) * 8));
        const __hip_bfloat16* hb = (const __hip_bfloat16*)&v;
#pragma unroll
        for (int i = 0; i < 8; ++i) a[i] += __bfloat162float(hb[i]);
    }
#pragma unroll
    for (int m = 4; m <= 32; m <<= 1)
#pragma unroll
        for (int i = 0; i < 8; ++i) a[i] += __shfl_xor(a[i], m, 64);
    if (j == 0) {
        float inv = 1.f / fmaxf((float)(end - beg), 1.f);
        __bf16 tmp[8];
#pragma unroll
        for (int i = 0; i < 8; ++i) tmp[i] = (__bf16)(a[i] * inv);
        *(uint4*)(acat + (size_t)(node >> 7) * (512 * 128) + (size_t)(slice * 4 + c) * 1024 +
                  (size_t)((node & 127) * 8)) = *(const uint4*)tmp;
    }
}

// layers 2/3: gathers h-half (chunks 64..127, 512 feats) of src buffer (Kc=1024),
// writes mean-half (chunks 0..63) of dst buffer. 16 slices x 32 feats.
__global__ __launch_bounds__(256) void k_agg2(const __bf16* __restrict__ srcbuf,
                                              const int* __restrict__ off,
                                              const int* __restrict__ csr,
                                              __bf16* __restrict__ dstbuf) {
    int bid = blockIdx.x;
    int slice = bid & 15, group = bid >> 4;
    int wave = threadIdx.x >> 6, lane = threadIdx.x & 63;
    int node = group * 4 + wave;
    int j = lane >> 2, c = lane & 3;
    int beg = off[node], end = off[node + 1];
    const __bf16* src = srcbuf + (size_t)(64 + slice * 4 + c) * 1024;
    float a[8] = {};
    for (int e = beg + j; e < end; e += 16) {
        int s = csr[e];
        uint4 v = *(const uint4*)(src + (size_t)(s >> 7) * (1024 * 128) + (size_t)((s & 127) * 8));
        const __hip_bfloat16* hb = (const __hip_bfloat16*)&v;
#pragma unroll
        for (int i = 0; i < 8; ++i) a[i] += __bfloat162float(hb[i]);
    }
#pragma unroll
    for (int m = 4; m <= 32; m <<= 1)
#pragma unroll
        for (int i = 0; i < 8; ++i) a[i] += __shfl_xor(a[i], m, 64);
    if (j == 0) {
        float inv = 1.f / fmaxf((float)(end - beg), 1.f);
        __bf16 tmp[8];
#pragma unroll
        for (int i = 0; i < 8; ++i) tmp[i] = (__bf16)(a[i] * inv);
        *(uint4*)(dstbuf + (size_t)(node >> 7) * (1024 * 128) + (size_t)(slice * 4 + c) * 1024 +
                  (size_t)((node & 127) * 8)) = *(const uint4*)tmp;
    }
}

// ---------------- bf16 MFMA GEMM, swizzled operands ----------------
// OUTMODE: 0 = bf16 swizzled; 2 = fp32 row-major.

template <bool RELU, int OUTMODE>
__global__ __launch_bounds__(256) void k_gemm(const __bf16* __restrict__ A, int K, int M,
                                              const __bf16* __restrict__ B,
                                              const float* __restrict__ bias,
                                              __bf16* __restrict__ osw, int Kc, int coff,
                                              float* __restrict__ of32, int ldf,
                                              int rtiles, int ctlog2) {
    constexpr int SMEM = (OUTMODE == 2) ? 34816 : 32768;
    __shared__ char smem[SMEM];
    __bf16* Alds = (__bf16*)smem;
    __bf16* Blds = (__bf16*)(smem + 16384);

    int bid = blockIdx.x;
    int xcd = bid & 7, local = bid >> 3;
    int cmask = (1 << ctlog2) - 1;
    int colTile = local & cmask;
    int rowTile = (local >> ctlog2) * 8 + xcd;
    if (rowTile >= rtiles) return;

    const __bf16* Atile = A + (size_t)rowTile * ((size_t)K * 128);
    const __bf16* Btile = B + (size_t)colTile * ((size_t)K * 128);

    int tid = threadIdx.x;
    int wave = tid >> 6, lane = tid & 63;
    int wr = wave >> 1, wc = wave & 1;
    int quad = lane >> 4, l16 = lane & 15;

    f32x4 acc[4][4] = {};

    for (int k0 = 0; k0 < K; k0 += 64) {
        __syncthreads();
        const __bf16* gA = Atile + (size_t)k0 * 128;
        const __bf16* gB = Btile + (size_t)k0 * 128;
#pragma unroll
        for (int j = 0; j < 4; ++j) {
            int slot = (j * 256 + tid) * 8;
            load16_lds(gA + slot, Alds + slot);
            load16_lds(gB + slot, Blds + slot);
        }
        __syncthreads();
#pragma unroll
        for (int sp = 0; sp < 2; ++sp) {
            bf16x8 af[4], bf[4];
#pragma unroll
            for (int mi = 0; mi < 4; ++mi)
                af[mi] = *(const bf16x8*)(Alds + sp * 4096 + quad * 1024 +
                                          (wr * 64 + mi * 16 + l16) * 8);
#pragma unroll
            for (int ni = 0; ni < 4; ++ni)
                bf[ni] = *(const bf16x8*)(Blds + sp * 4096 + quad * 1024 +
                                          (wc * 64 + ni * 16 + l16) * 8);
#pragma unroll
            for (int mi = 0; mi < 4; ++mi)
#pragma unroll
                for (int ni = 0; ni < 4; ++ni)
                    acc[mi][ni] = __builtin_amdgcn_mfma_f32_16x16x32_bf16(
                        af[mi], bf[ni], acc[mi][ni], 0, 0, 0);
        }
    }

    int col0 = colTile * 128;
    int row0 = rowTile * 128;
    __syncthreads();

    if (OUTMODE == 0) {
        __bf16* cb = (__bf16*)smem;   // [16 chunks][128 rows][8]
#pragma unroll
        for (int ni = 0; ni < 4; ++ni) {
            int ct = wc * 64 + ni * 16 + l16;
            float bv = bias[col0 + ct];
#pragma unroll
            for (int mi = 0; mi < 4; ++mi) {
                int rb = wr * 64 + mi * 16 + quad * 4;
#pragma unroll
                for (int r = 0; r < 4; ++r) {
                    float v = acc[mi][ni][r] + bv;
                    if (RELU) v = fmaxf(v, 0.f);
                    cb[(ct >> 3) * 1024 + (rb + r) * 8 + (ct & 7)] = (__bf16)v;
                }
            }
        }
        __syncthreads();
        __bf16* dst = osw + (size_t)rowTile * ((size_t)Kc * 128) +
                      (size_t)((coff + col0) >> 3) * 1024;
#pragma unroll
        for (int p2 = 0; p2 < 8; ++p2) {
            int idx = (p2 * 256 + tid) * 8;
            *(uint4*)(dst + idx) = *(const uint4*)(cb + idx);
        }
    } else {
        float* cf = (float*)smem;   // [128][68] fp32, two 64-col halves
#pragma unroll
        for (int h = 0; h < 2; ++h) {
            if (wc == h) {
#pragma unroll
                for (int ni = 0; ni < 4; ++ni) {
                    int ctl = ni * 16 + l16;
                    float bv = bias[col0 + h * 64 + ctl];
#pragma unroll
                    for (int mi = 0; mi < 4; ++mi) {
                        int rb = wr * 64 + mi * 16 + quad * 4;
#pragma unroll
                        for (int r = 0; r < 4; ++r) {
                            float v = acc[mi][ni][r] + bv;
                            if (RELU) v = fmaxf(v, 0.f);
                            cf[(rb + r) * 68 + ctl] = v;
                        }
                    }
                }
            }
            __syncthreads();
            int chunk = tid & 15, rl = tid >> 4;
#pragma unroll
            for (int p2 = 0; p2 < 8; ++p2) {
                int rt = p2 * 16 + rl;
                int row = row0 + rt;
                if (row < M) {
                    float4 v = *(const float4*)(cf + rt * 68 + chunk * 4);
                    *(float4*)(of32 + (size_t)row * ldf + col0 + h * 64 + chunk * 4) = v;
                }
            }
            __syncthreads();
        }
    }
}

// ---------------- launch ----------------

extern "C" void kernel_launch(void* const* d_in, const int* in_sizes, int n_in,
                              void* d_out, int out_size, void* d_ws, size_t ws_size,
                              hipStream_t stream) {
    const float* x   = (const float*)d_in[0];
    const int*   ei  = (const int*)d_in[1];
    const float* Wl1 = (const float*)d_in[2];
    const float* bl1 = (const float*)d_in[3];
    const float* Wr1 = (const float*)d_in[4];
    const float* Wl2 = (const float*)d_in[5];
    const float* bl2 = (const float*)d_in[6];
    const float* Wr2 = (const float*)d_in[7];
    const float* Wl3 = (const float*)d_in[8];
    const float* bl3 = (const float*)d_in[9];
    const float* Wr3 = (const float*)d_in[10];
    const float* Wfc = (const float*)d_in[11];
    const float* bfc = (const float*)d_in[12];
    float* out = (float*)d_out;

    const int NN = N_NODES, E = N_EDGES;
    const int NB = (NN + 1023) / 1024;

    char* p = (char*)d_ws;
    auto alloc = [&](size_t bytes) {
        char* r = p;
        p += (bytes + 511) & ~(size_t)511;
        return r;
    };
    int* cnt   = (int*)alloc((size_t)NN * 4);
    int* off   = (int*)alloc((size_t)(NN + 1) * 4);
    int* cur   = (int*)alloc((size_t)NN * 4);
    int* csr   = (int*)alloc((size_t)E * 4);
    int* bsum  = (int*)alloc((size_t)NB * 4);
    int* carry = (int*)alloc((size_t)NB * 4);
    __bf16* Acat1 = (__bf16*)alloc((size_t)MPAD * 512 * 2);    // swz [mean|x]
    __bf16* Acat2 = (__bf16*)alloc((size_t)MPAD * 1024 * 2);   // swz [mean|h1]
    __bf16* Acat3 = (__bf16*)alloc((size_t)MPAD * 1024 * 2);   // swz [mean|h2]
    __bf16* Wt1 = (__bf16*)alloc((size_t)512 * 512 * 2);
    __bf16* Wt2 = (__bf16*)alloc((size_t)512 * 1024 * 2);
    __bf16* Wt3 = (__bf16*)alloc((size_t)1024 * 1024 * 2);
    __bf16* Wt4 = (__bf16*)alloc((size_t)512 * 1024 * 2);
    __bf16* H3 = Acat2;   // alias: Acat2 dead after GEMM2 reads it

    // CSR build
    hipMemsetAsync(cnt, 0, (size_t)NN * 4, stream);
    k_count<<<(E + 255) / 256, 256, 0, stream>>>(ei, E, cnt);
    k_scan_block<<<NB, 1024, 0, stream>>>(cnt, off, bsum, NN);
    k_scan_carry<<<1, 64, 0, stream>>>(bsum, carry, NB, off, NN);
    k_scan_add<<<NB, 1024, 0, stream>>>(off, cur, carry, NN);
    k_fill<<<(E + 255) / 256, 256, 0, stream>>>(ei, E, cur, csr);

    // fused weight transposes
    TDescs td;
    td.d[0] = {Wl1, Wt1, 256, 512, 512, 0, 0};
    td.d[1] = {Wr1, Wt1, 256, 512, 512, 256, 128};
    td.d[2] = {Wl2, Wt2, 512, 512, 1024, 0, 256};
    td.d[3] = {Wr2, Wt2, 512, 512, 1024, 512, 512};
    td.d[4] = {Wl3, Wt3, 512, 1024, 1024, 0, 768};
    td.d[5] = {Wr3, Wt3, 512, 1024, 1024, 512, 1280};
    td.d[6] = {Wfc, Wt4, 1024, 512, 1024, 0, 1792};
    k_transpose_all<<<2304, dim3(32, 8), 0, stream>>>(td);

    // x -> swizzled bf16 right half of Acat1
    k_convx<<<dim3(157, 16), 256, 0, stream>>>(x, Acat1);

    int rtiles = (NN + 127) / 128;        // 157
    int rg = ((rtiles + 7) / 8) * 8;      // 160

    // Layer 1
    k_agg1<<<(NN / 4) * 8, 256, 0, stream>>>(off, csr, Acat1);
    k_gemm<true, 0><<<rg * 4, 256, 0, stream>>>(
        Acat1, 512, NN, Wt1, bl1, Acat2, 1024, 512, nullptr, 0, rtiles, 2);

    // Layer 2
    k_agg2<<<(NN / 4) * 16, 256, 0, stream>>>(Acat2, off, csr, Acat2);
    k_gemm<true, 0><<<rg * 4, 256, 0, stream>>>(
        Acat2, 1024, NN, Wt2, bl2, Acat3, 1024, 512, nullptr, 0, rtiles, 2);

    // Layer 3
    k_agg2<<<(NN / 4) * 16, 256, 0, stream>>>(Acat3, off, csr, Acat3);
    k_gemm<true, 0><<<rg * 8, 256, 0, stream>>>(
        Acat3, 1024, NN, Wt3, bl3, H3, 1024, 0, nullptr, 0, rtiles, 3);

    // FC (fp32 row-major out, no relu)
    k_gemm<false, 2><<<rg * 4, 256, 0, stream>>>(
        H3, 1024, NN, Wt4, bfc, nullptr, 0, 0, out, 512, rtiles, 2);
}

// Round 8
// 525.023 us; speedup vs baseline: 1.0565x; 1.0565x over previous
//
#include <hip/hip_runtime.h>
#include <hip/hip_bf16.h>

// MolecularGraphNet: 3x SAGEConv(mean) + Linear, on MI355X.
//  - All activations in chunk-linear swizzled format:
//      elem(r,k) of [rows,K] at (r>>7)*(K*128) + (k>>3)*1024 + (r&127)*8 + (k&7)
//  - GEMM: 128x128 tile, BK=64, global_load_lds(16B), XCD-aware remap.
//  - Aggregation: XCD-sliced (fslice = bid&7 -> ~1.3-2.6 MB/XCD, L2-resident),
//    lane = (node-slot x feat-chunk): each lane privately accumulates 8 feats
//    over ALL the node's edges -> NO cross-lane reduce, no LDS, no shuffles.

typedef __bf16 bf16x8 __attribute__((ext_vector_type(8)));
typedef float  f32x4  __attribute__((ext_vector_type(4)));

#define N_NODES 20000
#define N_EDGES 320000
#define MPAD 20096   // 157*128

__device__ __forceinline__ int clampi(int v, int lo, int hi) {
    return v < lo ? lo : (v > hi ? hi : v);
}

__device__ __forceinline__ void load16_lds(const void* g, void* l) {
    __builtin_amdgcn_global_load_lds(
        (const __attribute__((address_space(1))) void*)g,
        (__attribute__((address_space(3))) void*)l, 16, 0, 0);
}

// ---------------- CSR build ----------------

__global__ void k_count(const int* __restrict__ ei, int E, int* __restrict__ cnt) {
    int e = blockIdx.x * blockDim.x + threadIdx.x;
    if (e < E) atomicAdd(&cnt[clampi(ei[E + e], 0, N_NODES - 1)], 1);
}

__global__ __launch_bounds__(1024) void k_scan_block(const int* __restrict__ cnt,
                                                     int* __restrict__ off,
                                                     int* __restrict__ bsum, int n) {
    __shared__ int sm[1024];
    int b = blockIdx.x, tid = threadIdx.x;
    int i = b * 1024 + tid;
    int v = (i < n) ? cnt[i] : 0;
    sm[tid] = v;
    __syncthreads();
    for (int s = 1; s < 1024; s <<= 1) {
        int t = (tid >= s) ? sm[tid - s] : 0;
        __syncthreads();
        sm[tid] += t;
        __syncthreads();
    }
    if (i < n) off[i] = sm[tid] - v;
    if (tid == 1023) bsum[b] = sm[1023];
}

__global__ void k_scan_carry(const int* __restrict__ bsum, int* __restrict__ carry,
                             int nb, int* __restrict__ off, int n) {
    if (threadIdx.x == 0 && blockIdx.x == 0) {
        int acc = 0;
        for (int b = 0; b < nb; ++b) { carry[b] = acc; acc += bsum[b]; }
        off[n] = acc;
    }
}

__global__ __launch_bounds__(1024) void k_scan_add(int* __restrict__ off,
                                                   int* __restrict__ cur,
                                                   const int* __restrict__ carry, int n) {
    int i = blockIdx.x * 1024 + threadIdx.x;
    if (i < n) {
        int v = off[i] + carry[blockIdx.x];
        off[i] = v;
        cur[i] = v;
    }
}

__global__ void k_fill(const int* __restrict__ ei, int E,
                       int* __restrict__ cur, int* __restrict__ csr) {
    int e = blockIdx.x * blockDim.x + threadIdx.x;
    if (e < E) {
        int dst = clampi(ei[E + e], 0, N_NODES - 1);
        int src = clampi(ei[e], 0, N_NODES - 1);
        int pos = atomicAdd(&cur[dst], 1);
        if (pos >= 0 && pos < E) csr[pos] = src;
    }
}

// ---------------- fused weight transposes: W fp32 [K,N] -> swizzled bf16 [N,KT] ----------------

struct TDesc { const float* W; __bf16* Wt; int K, N, KT, koff, tile0; };
struct TDescs { TDesc d[7]; };

__global__ void k_transpose_all(TDescs ds) {
    __shared__ float tile[32][33];
    int b = blockIdx.x;
    int di = 0;
#pragma unroll
    for (int i = 1; i < 7; ++i)
        if (b >= ds.d[i].tile0) di = i;
    const float* W = ds.d[di].W;
    __bf16* Wt = ds.d[di].Wt;
    int N = ds.d[di].N, KT = ds.d[di].KT, koff = ds.d[di].koff;
    int t = b - ds.d[di].tile0;
    int ntn = N >> 5;
    int nb = (t % ntn) * 32, kb = (t / ntn) * 32;
    for (int i = 0; i < 32; i += 8) {
        int k = kb + threadIdx.y + i, n = nb + threadIdx.x;
        tile[threadIdx.y + i][threadIdx.x] = W[(size_t)k * N + n];
    }
    __syncthreads();
    for (int i = 0; i < 32; i += 8) {
        int n = nb + threadIdx.y + i, k = koff + kb + threadIdx.x;
        size_t o = (size_t)(n >> 7) * ((size_t)KT * 128) + (size_t)(k >> 3) * 1024 +
                   (size_t)((n & 127) * 8) + (k & 7);
        Wt[o] = (__bf16)tile[threadIdx.x][threadIdx.y + i];
    }
}

// ---------------- x fp32 -> swizzled bf16 (right half of Acat1) ----------------

__global__ __launch_bounds__(256) void k_convx(const float* __restrict__ x,
                                               __bf16* __restrict__ acat) {
    int tile = blockIdx.x;
    int chunk = blockIdx.y * 2 + (threadIdx.x >> 7);
    int nl = threadIdx.x & 127;
    int node = tile * 128 + nl;
    __bf16 tmp[8] = {};
    if (node < N_NODES) {
        float4 u = *(const float4*)(x + (size_t)node * 256 + chunk * 8);
        float4 w = *(const float4*)(x + (size_t)node * 256 + chunk * 8 + 4);
        tmp[0] = (__bf16)u.x; tmp[1] = (__bf16)u.y; tmp[2] = (__bf16)u.z; tmp[3] = (__bf16)u.w;
        tmp[4] = (__bf16)w.x; tmp[5] = (__bf16)w.y; tmp[6] = (__bf16)w.z; tmp[7] = (__bf16)w.w;
    }
    *(uint4*)(acat + (size_t)tile * (512 * 128) + (size_t)(32 + chunk) * 1024 +
              (size_t)(nl * 8)) = *(const uint4*)tmp;
}

// ---------------- XCD-sliced, reduce-free aggregation (CSR gather, mean) ----------------
// Lane = (node-slot, chunk). Each lane accumulates its own 8 feats over ALL the
// node's edges: no cross-lane combine. Slot lanes load 64/128 B contiguous/edge.

// layer 1: Acat1 (K=512): src = h chunks 32..63, dst = mean chunks 0..31.
// Wave = 16 slots x 4 chunks; fslice = bid&7 -> 32 feats (1.3 MB/XCD slice).
__global__ __launch_bounds__(256) void k_agg1(const int* __restrict__ off,
                                              const int* __restrict__ csr,
                                              __bf16* __restrict__ acat) {
    int bid = blockIdx.x;
    int fs = bid & 7, group = bid >> 3;
    int wave = threadIdx.x >> 6, lane = threadIdx.x & 63;
    int slot = lane >> 2, c = lane & 3;
    int node = group * 64 + wave * 16 + slot;
    if (node >= N_NODES) return;
    int beg = off[node], end = off[node + 1];
    const __bf16* src = acat + (size_t)(32 + fs * 4 + c) * 1024;
    float a[8] = {};
    for (int e = beg; e < end; ++e) {
        int s = csr[e];
        uint4 v = *(const uint4*)(src + (size_t)(s >> 7) * (512 * 128) +
                                  (size_t)((s & 127) * 8));
        const __hip_bfloat16* hb = (const __hip_bfloat16*)&v;
#pragma unroll
        for (int i = 0; i < 8; ++i) a[i] += __bfloat162float(hb[i]);
    }
    float inv = 1.f / fmaxf((float)(end - beg), 1.f);
    __bf16 tmp[8];
#pragma unroll
    for (int i = 0; i < 8; ++i) tmp[i] = (__bf16)(a[i] * inv);
    *(uint4*)(acat + (size_t)(node >> 7) * (512 * 128) + (size_t)(fs * 4 + c) * 1024 +
              (size_t)((node & 127) * 8)) = *(const uint4*)tmp;
}

// layers 2/3: src buffer (K=1024) h chunks 64..127 -> dst buffer mean chunks 0..63.
// Wave = 8 slots x 8 chunks; fslice = bid&7 -> 64 feats (2.6 MB/XCD slice).
__global__ __launch_bounds__(256) void k_agg2(const __bf16* __restrict__ srcbuf,
                                              const int* __restrict__ off,
                                              const int* __restrict__ csr,
                                              __bf16* __restrict__ dstbuf) {
    int bid = blockIdx.x;
    int fs = bid & 7, group = bid >> 3;
    int wave = threadIdx.x >> 6, lane = threadIdx.x & 63;
    int slot = lane >> 3, c = lane & 7;
    int node = group * 32 + wave * 8 + slot;   // grid exact: 625*32 = 20000
    int beg = off[node], end = off[node + 1];
    const __bf16* src = srcbuf + (size_t)(64 + fs * 8 + c) * 1024;
    float a[8] = {};
    for (int e = beg; e < end; ++e) {
        int s = csr[e];
        uint4 v = *(const uint4*)(src + (size_t)(s >> 7) * (1024 * 128) +
                                  (size_t)((s & 127) * 8));
        const __hip_bfloat16* hb = (const __hip_bfloat16*)&v;
#pragma unroll
        for (int i = 0; i < 8; ++i) a[i] += __bfloat162float(hb[i]);
    }
    float inv = 1.f / fmaxf((float)(end - beg), 1.f);
    __bf16 tmp[8];
#pragma unroll
    for (int i = 0; i < 8; ++i) tmp[i] = (__bf16)(a[i] * inv);
    *(uint4*)(dstbuf + (size_t)(node >> 7) * (1024 * 128) + (size_t)(fs * 8 + c) * 1024 +
              (size_t)((node & 127) * 8)) = *(const uint4*)tmp;
}

// ---------------- bf16 MFMA GEMM, swizzled operands ----------------
// OUTMODE: 0 = bf16 swizzled; 2 = fp32 row-major.

template <bool RELU, int OUTMODE>
__global__ __launch_bounds__(256) void k_gemm(const __bf16* __restrict__ A, int K, int M,
                                              const __bf16* __restrict__ B,
                                              const float* __restrict__ bias,
                                              __bf16* __restrict__ osw, int Kc, int coff,
                                              float* __restrict__ of32, int ldf,
                                              int rtiles, int ctlog2) {
    constexpr int SMEM = (OUTMODE == 2) ? 34816 : 32768;
    __shared__ char smem[SMEM];
    __bf16* Alds = (__bf16*)smem;
    __bf16* Blds = (__bf16*)(smem + 16384);

    int bid = blockIdx.x;
    int xcd = bid & 7, local = bid >> 3;
    int cmask = (1 << ctlog2) - 1;
    int colTile = local & cmask;
    int rowTile = (local >> ctlog2) * 8 + xcd;
    if (rowTile >= rtiles) return;

    const __bf16* Atile = A + (size_t)rowTile * ((size_t)K * 128);
    const __bf16* Btile = B + (size_t)colTile * ((size_t)K * 128);

    int tid = threadIdx.x;
    int wave = tid >> 6, lane = tid & 63;
    int wr = wave >> 1, wc = wave & 1;
    int quad = lane >> 4, l16 = lane & 15;

    f32x4 acc[4][4] = {};

    for (int k0 = 0; k0 < K; k0 += 64) {
        __syncthreads();
        const __bf16* gA = Atile + (size_t)k0 * 128;
        const __bf16* gB = Btile + (size_t)k0 * 128;
#pragma unroll
        for (int j = 0; j < 4; ++j) {
            int slot = (j * 256 + tid) * 8;
            load16_lds(gA + slot, Alds + slot);
            load16_lds(gB + slot, Blds + slot);
        }
        __syncthreads();
#pragma unroll
        for (int sp = 0; sp < 2; ++sp) {
            bf16x8 af[4], bf[4];
#pragma unroll
            for (int mi = 0; mi < 4; ++mi)
                af[mi] = *(const bf16x8*)(Alds + sp * 4096 + quad * 1024 +
                                          (wr * 64 + mi * 16 + l16) * 8);
#pragma unroll
            for (int ni = 0; ni < 4; ++ni)
                bf[ni] = *(const bf16x8*)(Blds + sp * 4096 + quad * 1024 +
                                          (wc * 64 + ni * 16 + l16) * 8);
#pragma unroll
            for (int mi = 0; mi < 4; ++mi)
#pragma unroll
                for (int ni = 0; ni < 4; ++ni)
                    acc[mi][ni] = __builtin_amdgcn_mfma_f32_16x16x32_bf16(
                        af[mi], bf[ni], acc[mi][ni], 0, 0, 0);
        }
    }

    int col0 = colTile * 128;
    int row0 = rowTile * 128;
    __syncthreads();

    if (OUTMODE == 0) {
        __bf16* cb = (__bf16*)smem;   // [16 chunks][128 rows][8]
#pragma unroll
        for (int ni = 0; ni < 4; ++ni) {
            int ct = wc * 64 + ni * 16 + l16;
            float bv = bias[col0 + ct];
#pragma unroll
            for (int mi = 0; mi < 4; ++mi) {
                int rb = wr * 64 + mi * 16 + quad * 4;
#pragma unroll
                for (int r = 0; r < 4; ++r) {
                    float v = acc[mi][ni][r] + bv;
                    if (RELU) v = fmaxf(v, 0.f);
                    cb[(ct >> 3) * 1024 + (rb + r) * 8 + (ct & 7)] = (__bf16)v;
                }
            }
        }
        __syncthreads();
        __bf16* dst = osw + (size_t)rowTile * ((size_t)Kc * 128) +
                      (size_t)((coff + col0) >> 3) * 1024;
#pragma unroll
        for (int p2 = 0; p2 < 8; ++p2) {
            int idx = (p2 * 256 + tid) * 8;
            *(uint4*)(dst + idx) = *(const uint4*)(cb + idx);
        }
    } else {
        float* cf = (float*)smem;   // [128][68] fp32, two 64-col halves
#pragma unroll
        for (int h = 0; h < 2; ++h) {
            if (wc == h) {
#pragma unroll
                for (int ni = 0; ni < 4; ++ni) {
                    int ctl = ni * 16 + l16;
                    float bv = bias[col0 + h * 64 + ctl];
#pragma unroll
                    for (int mi = 0; mi < 4; ++mi) {
                        int rb = wr * 64 + mi * 16 + quad * 4;
#pragma unroll
                        for (int r = 0; r < 4; ++r) {
                            float v = acc[mi][ni][r] + bv;
                            if (RELU) v = fmaxf(v, 0.f);
                            cf[(rb + r) * 68 + ctl] = v;
                        }
                    }
                }
            }
            __syncthreads();
            int chunk = tid & 15, rl = tid >> 4;
#pragma unroll
            for (int p2 = 0; p2 < 8; ++p2) {
                int rt = p2 * 16 + rl;
                int row = row0 + rt;
                if (row < M) {
                    float4 v = *(const float4*)(cf + rt * 68 + chunk * 4);
                    *(float4*)(of32 + (size_t)row * ldf + col0 + h * 64 + chunk * 4) = v;
                }
            }
            __syncthreads();
        }
    }
}

// ---------------- launch ----------------

extern "C" void kernel_launch(void* const* d_in, const int* in_sizes, int n_in,
                              void* d_out, int out_size, void* d_ws, size_t ws_size,
                              hipStream_t stream) {
    const float* x   = (const float*)d_in[0];
    const int*   ei  = (const int*)d_in[1];
    const float* Wl1 = (const float*)d_in[2];
    const float* bl1 = (const float*)d_in[3];
    const float* Wr1 = (const float*)d_in[4];
    const float* Wl2 = (const float*)d_in[5];
    const float* bl2 = (const float*)d_in[6];
    const float* Wr2 = (const float*)d_in[7];
    const float* Wl3 = (const float*)d_in[8];
    const float* bl3 = (const float*)d_in[9];
    const float* Wr3 = (const float*)d_in[10];
    const float* Wfc = (const float*)d_in[11];
    const float* bfc = (const float*)d_in[12];
    float* out = (float*)d_out;

    const int NN = N_NODES, E = N_EDGES;
    const int NB = (NN + 1023) / 1024;

    char* p = (char*)d_ws;
    auto alloc = [&](size_t bytes) {
        char* r = p;
        p += (bytes + 511) & ~(size_t)511;
        return r;
    };
    int* cnt   = (int*)alloc((size_t)NN * 4);
    int* off   = (int*)alloc((size_t)(NN + 1) * 4);
    int* cur   = (int*)alloc((size_t)NN * 4);
    int* csr   = (int*)alloc((size_t)E * 4);
    int* bsum  = (int*)alloc((size_t)NB * 4);
    int* carry = (int*)alloc((size_t)NB * 4);
    __bf16* Acat1 = (__bf16*)alloc((size_t)MPAD * 512 * 2);    // swz [mean|x]
    __bf16* Acat2 = (__bf16*)alloc((size_t)MPAD * 1024 * 2);   // swz [mean|h1]
    __bf16* Acat3 = (__bf16*)alloc((size_t)MPAD * 1024 * 2);   // swz [mean|h2]
    __bf16* Wt1 = (__bf16*)alloc((size_t)512 * 512 * 2);
    __bf16* Wt2 = (__bf16*)alloc((size_t)512 * 1024 * 2);
    __bf16* Wt3 = (__bf16*)alloc((size_t)1024 * 1024 * 2);
    __bf16* Wt4 = (__bf16*)alloc((size_t)512 * 1024 * 2);
    __bf16* H3 = Acat2;   // alias: Acat2 dead after GEMM2 reads it

    // CSR build
    hipMemsetAsync(cnt, 0, (size_t)NN * 4, stream);
    k_count<<<(E + 255) / 256, 256, 0, stream>>>(ei, E, cnt);
    k_scan_block<<<NB, 1024, 0, stream>>>(cnt, off, bsum, NN);
    k_scan_carry<<<1, 64, 0, stream>>>(bsum, carry, NB, off, NN);
    k_scan_add<<<NB, 1024, 0, stream>>>(off, cur, carry, NN);
    k_fill<<<(E + 255) / 256, 256, 0, stream>>>(ei, E, cur, csr);

    // fused weight transposes
    TDescs td;
    td.d[0] = {Wl1, Wt1, 256, 512, 512, 0, 0};
    td.d[1] = {Wr1, Wt1, 256, 512, 512, 256, 128};
    td.d[2] = {Wl2, Wt2, 512, 512, 1024, 0, 256};
    td.d[3] = {Wr2, Wt2, 512, 512, 1024, 512, 512};
    td.d[4] = {Wl3, Wt3, 512, 1024, 1024, 0, 768};
    td.d[5] = {Wr3, Wt3, 512, 1024, 1024, 512, 1280};
    td.d[6] = {Wfc, Wt4, 1024, 512, 1024, 0, 1792};
    k_transpose_all<<<2304, dim3(32, 8), 0, stream>>>(td);

    // x -> swizzled bf16 right half of Acat1
    k_convx<<<dim3(157, 16), 256, 0, stream>>>(x, Acat1);

    int rtiles = (NN + 127) / 128;        // 157
    int rg = ((rtiles + 7) / 8) * 8;      // 160

    // Layer 1
    k_agg1<<<313 * 8, 256, 0, stream>>>(off, csr, Acat1);
    k_gemm<true, 0><<<rg * 4, 256, 0, stream>>>(
        Acat1, 512, NN, Wt1, bl1, Acat2, 1024, 512, nullptr, 0, rtiles, 2);

    // Layer 2
    k_agg2<<<625 * 8, 256, 0, stream>>>(Acat2, off, csr, Acat2);
    k_gemm<true, 0><<<rg * 4, 256, 0, stream>>>(
        Acat2, 1024, NN, Wt2, bl2, Acat3, 1024, 512, nullptr, 0, rtiles, 2);

    // Layer 3
    k_agg2<<<625 * 8, 256, 0, stream>>>(Acat3, off, csr, Acat3);
    k_gemm<true, 0><<<rg * 8, 256, 0, stream>>>(
        Acat3, 1024, NN, Wt3, bl3, H3, 1024, 0, nullptr, 0, rtiles, 3);

    // FC (fp32 row-major out, no relu)
    k_gemm<false, 2><<<rg * 4, 256, 0, stream>>>(
        H3, 1024, NN, Wt4, bfc, nullptr, 0, 0, out, 512, rtiles, 2);
}

// Round 9
// 499.793 us; speedup vs baseline: 1.1098x; 1.0505x over previous
//
#include <hip/hip_runtime.h>
#include <hip/hip_bf16.h>

// MolecularGraphNet: 3x SAGEConv(mean) + Linear, on MI355X.
//  - All activations in chunk-linear swizzled format:
//      elem(r,k) of [rows,K] at (r>>7)*(K*128) + (k>>3)*1024 + (r&127)*8 + (k&7)
//  - GEMM: 128x128 tile, BK=64, global_load_lds(16B), XCD-aware remap.
//  - Aggregation: XCD-sliced (fslice = bid&7, ~1.3-2.6 MB/XCD, L2-resident),
//    lane = (node-slot x feat-chunk), private accumulation (no shuffles),
//    4-wide unrolled edge loop with predicated tail -> 4 loads in flight/lane.

typedef __bf16 bf16x8 __attribute__((ext_vector_type(8)));
typedef float  f32x4  __attribute__((ext_vector_type(4)));

#define N_NODES 20000
#define N_EDGES 320000
#define MPAD 20096   // 157*128

__device__ __forceinline__ int clampi(int v, int lo, int hi) {
    return v < lo ? lo : (v > hi ? hi : v);
}

__device__ __forceinline__ void load16_lds(const void* g, void* l) {
    __builtin_amdgcn_global_load_lds(
        (const __attribute__((address_space(1))) void*)g,
        (__attribute__((address_space(3))) void*)l, 16, 0, 0);
}

// ---------------- CSR build ----------------

__global__ void k_count(const int* __restrict__ ei, int E, int* __restrict__ cnt) {
    int e = blockIdx.x * blockDim.x + threadIdx.x;
    if (e < E) atomicAdd(&cnt[clampi(ei[E + e], 0, N_NODES - 1)], 1);
}

__global__ __launch_bounds__(1024) void k_scan_block(const int* __restrict__ cnt,
                                                     int* __restrict__ off,
                                                     int* __restrict__ bsum, int n) {
    __shared__ int sm[1024];
    int b = blockIdx.x, tid = threadIdx.x;
    int i = b * 1024 + tid;
    int v = (i < n) ? cnt[i] : 0;
    sm[tid] = v;
    __syncthreads();
    for (int s = 1; s < 1024; s <<= 1) {
        int t = (tid >= s) ? sm[tid - s] : 0;
        __syncthreads();
        sm[tid] += t;
        __syncthreads();
    }
    if (i < n) off[i] = sm[tid] - v;
    if (tid == 1023) bsum[b] = sm[1023];
}

__global__ void k_scan_carry(const int* __restrict__ bsum, int* __restrict__ carry,
                             int nb, int* __restrict__ off, int n) {
    if (threadIdx.x == 0 && blockIdx.x == 0) {
        int acc = 0;
        for (int b = 0; b < nb; ++b) { carry[b] = acc; acc += bsum[b]; }
        off[n] = acc;
    }
}

__global__ __launch_bounds__(1024) void k_scan_add(int* __restrict__ off,
                                                   int* __restrict__ cur,
                                                   const int* __restrict__ carry, int n) {
    int i = blockIdx.x * 1024 + threadIdx.x;
    if (i < n) {
        int v = off[i] + carry[blockIdx.x];
        off[i] = v;
        cur[i] = v;
    }
}

__global__ void k_fill(const int* __restrict__ ei, int E,
                       int* __restrict__ cur, int* __restrict__ csr) {
    int e = blockIdx.x * blockDim.x + threadIdx.x;
    if (e < E) {
        int dst = clampi(ei[E + e], 0, N_NODES - 1);
        int src = clampi(ei[e], 0, N_NODES - 1);
        int pos = atomicAdd(&cur[dst], 1);
        if (pos >= 0 && pos < E) csr[pos] = src;
    }
}

// ---------------- fused weight transposes: W fp32 [K,N] -> swizzled bf16 [N,KT] ----------------

struct TDesc { const float* W; __bf16* Wt; int K, N, KT, koff, tile0; };
struct TDescs { TDesc d[7]; };

__global__ void k_transpose_all(TDescs ds) {
    __shared__ float tile[32][33];
    int b = blockIdx.x;
    int di = 0;
#pragma unroll
    for (int i = 1; i < 7; ++i)
        if (b >= ds.d[i].tile0) di = i;
    const float* W = ds.d[di].W;
    __bf16* Wt = ds.d[di].Wt;
    int N = ds.d[di].N, KT = ds.d[di].KT, koff = ds.d[di].koff;
    int t = b - ds.d[di].tile0;
    int ntn = N >> 5;
    int nb = (t % ntn) * 32, kb = (t / ntn) * 32;
    for (int i = 0; i < 32; i += 8) {
        int k = kb + threadIdx.y + i, n = nb + threadIdx.x;
        tile[threadIdx.y + i][threadIdx.x] = W[(size_t)k * N + n];
    }
    __syncthreads();
    for (int i = 0; i < 32; i += 8) {
        int n = nb + threadIdx.y + i, k = koff + kb + threadIdx.x;
        size_t o = (size_t)(n >> 7) * ((size_t)KT * 128) + (size_t)(k >> 3) * 1024 +
                   (size_t)((n & 127) * 8) + (k & 7);
        Wt[o] = (__bf16)tile[threadIdx.x][threadIdx.y + i];
    }
}

// ---------------- x fp32 -> swizzled bf16 (right half of Acat1) ----------------

__global__ __launch_bounds__(256) void k_convx(const float* __restrict__ x,
                                               __bf16* __restrict__ acat) {
    int tile = blockIdx.x;
    int chunk = blockIdx.y * 2 + (threadIdx.x >> 7);
    int nl = threadIdx.x & 127;
    int node = tile * 128 + nl;
    __bf16 tmp[8] = {};
    if (node < N_NODES) {
        float4 u = *(const float4*)(x + (size_t)node * 256 + chunk * 8);
        float4 w = *(const float4*)(x + (size_t)node * 256 + chunk * 8 + 4);
        tmp[0] = (__bf16)u.x; tmp[1] = (__bf16)u.y; tmp[2] = (__bf16)u.z; tmp[3] = (__bf16)u.w;
        tmp[4] = (__bf16)w.x; tmp[5] = (__bf16)w.y; tmp[6] = (__bf16)w.z; tmp[7] = (__bf16)w.w;
    }
    *(uint4*)(acat + (size_t)tile * (512 * 128) + (size_t)(32 + chunk) * 1024 +
              (size_t)(nl * 8)) = *(const uint4*)tmp;
}

// ---------------- XCD-sliced, reduce-free aggregation, 4-wide MLP ----------------
// Lane = (node-slot, chunk); private accumulation over the node's edges.
// Edge loop unrolled 4-wide: 4 independent uint4 loads in flight per lane,
// predicated accumulate (clamped index keeps OOB loads legal).

__device__ __forceinline__ void acc_masked(float* a, uint4 v, float w) {
    const __hip_bfloat16* hb = (const __hip_bfloat16*)&v;
#pragma unroll
    for (int i = 0; i < 8; ++i) a[i] = fmaf(w, __bfloat162float(hb[i]), a[i]);
}

// layer 1: Acat1 (K=512): src = h chunks 32..63, dst = mean chunks 0..31.
// Wave = 16 slots x 4 chunks; fslice = bid&7 -> 32 feats (1.3 MB/XCD slice).
__global__ __launch_bounds__(256) void k_agg1(const int* __restrict__ off,
                                              const int* __restrict__ csr,
                                              __bf16* __restrict__ acat) {
    int bid = blockIdx.x;
    int fs = bid & 7, group = bid >> 3;
    int wave = threadIdx.x >> 6, lane = threadIdx.x & 63;
    int slot = lane >> 2, c = lane & 3;
    int node = group * 64 + wave * 16 + slot;
    if (node >= N_NODES) return;
    int beg = off[node], end = off[node + 1];
    const __bf16* src = acat + (size_t)(32 + fs * 4 + c) * 1024;
    float a[8] = {};
    for (int e = beg; e < end; e += 4) {
        int i1 = e + 1, i2 = e + 2, i3 = e + 3;
        int last = end - 1;
        int s0 = csr[e];
        int s1 = csr[i1 < end ? i1 : last];
        int s2 = csr[i2 < end ? i2 : last];
        int s3 = csr[i3 < end ? i3 : last];
        uint4 v0 = *(const uint4*)(src + (size_t)(s0 >> 7) * (512 * 128) + ((s0 & 127) * 8));
        uint4 v1 = *(const uint4*)(src + (size_t)(s1 >> 7) * (512 * 128) + ((s1 & 127) * 8));
        uint4 v2 = *(const uint4*)(src + (size_t)(s2 >> 7) * (512 * 128) + ((s2 & 127) * 8));
        uint4 v3 = *(const uint4*)(src + (size_t)(s3 >> 7) * (512 * 128) + ((s3 & 127) * 8));
        acc_masked(a, v0, 1.f);
        acc_masked(a, v1, i1 < end ? 1.f : 0.f);
        acc_masked(a, v2, i2 < end ? 1.f : 0.f);
        acc_masked(a, v3, i3 < end ? 1.f : 0.f);
    }
    float inv = 1.f / fmaxf((float)(end - beg), 1.f);
    __bf16 tmp[8];
#pragma unroll
    for (int i = 0; i < 8; ++i) tmp[i] = (__bf16)(a[i] * inv);
    *(uint4*)(acat + (size_t)(node >> 7) * (512 * 128) + (size_t)(fs * 4 + c) * 1024 +
              (size_t)((node & 127) * 8)) = *(const uint4*)tmp;
}

// layers 2/3: src buffer (K=1024) h chunks 64..127 -> dst buffer mean chunks 0..63.
// Wave = 8 slots x 8 chunks; fslice = bid&7 -> 64 feats (2.6 MB/XCD slice).
__global__ __launch_bounds__(256) void k_agg2(const __bf16* __restrict__ srcbuf,
                                              const int* __restrict__ off,
                                              const int* __restrict__ csr,
                                              __bf16* __restrict__ dstbuf) {
    int bid = blockIdx.x;
    int fs = bid & 7, group = bid >> 3;
    int wave = threadIdx.x >> 6, lane = threadIdx.x & 63;
    int slot = lane >> 3, c = lane & 7;
    int node = group * 32 + wave * 8 + slot;   // grid exact: 625*32 = 20000
    int beg = off[node], end = off[node + 1];
    const __bf16* src = srcbuf + (size_t)(64 + fs * 8 + c) * 1024;
    float a[8] = {};
    for (int e = beg; e < end; e += 4) {
        int i1 = e + 1, i2 = e + 2, i3 = e + 3;
        int last = end - 1;
        int s0 = csr[e];
        int s1 = csr[i1 < end ? i1 : last];
        int s2 = csr[i2 < end ? i2 : last];
        int s3 = csr[i3 < end ? i3 : last];
        uint4 v0 = *(const uint4*)(src + (size_t)(s0 >> 7) * (1024 * 128) + ((s0 & 127) * 8));
        uint4 v1 = *(const uint4*)(src + (size_t)(s1 >> 7) * (1024 * 128) + ((s1 & 127) * 8));
        uint4 v2 = *(const uint4*)(src + (size_t)(s2 >> 7) * (1024 * 128) + ((s2 & 127) * 8));
        uint4 v3 = *(const uint4*)(src + (size_t)(s3 >> 7) * (1024 * 128) + ((s3 & 127) * 8));
        acc_masked(a, v0, 1.f);
        acc_masked(a, v1, i1 < end ? 1.f : 0.f);
        acc_masked(a, v2, i2 < end ? 1.f : 0.f);
        acc_masked(a, v3, i3 < end ? 1.f : 0.f);
    }
    float inv = 1.f / fmaxf((float)(end - beg), 1.f);
    __bf16 tmp[8];
#pragma unroll
    for (int i = 0; i < 8; ++i) tmp[i] = (__bf16)(a[i] * inv);
    *(uint4*)(dstbuf + (size_t)(node >> 7) * (1024 * 128) + (size_t)(fs * 8 + c) * 1024 +
              (size_t)((node & 127) * 8)) = *(const uint4*)tmp;
}

// ---------------- bf16 MFMA GEMM, swizzled operands ----------------
// OUTMODE: 0 = bf16 swizzled; 2 = fp32 row-major.

template <bool RELU, int OUTMODE>
__global__ __launch_bounds__(256) void k_gemm(const __bf16* __restrict__ A, int K, int M,
                                              const __bf16* __restrict__ B,
                                              const float* __restrict__ bias,
                                              __bf16* __restrict__ osw, int Kc, int coff,
                                              float* __restrict__ of32, int ldf,
                                              int rtiles, int ctlog2) {
    constexpr int SMEM = (OUTMODE == 2) ? 34816 : 32768;
    __shared__ char smem[SMEM];
    __bf16* Alds = (__bf16*)smem;
    __bf16* Blds = (__bf16*)(smem + 16384);

    int bid = blockIdx.x;
    int xcd = bid & 7, local = bid >> 3;
    int cmask = (1 << ctlog2) - 1;
    int colTile = local & cmask;
    int rowTile = (local >> ctlog2) * 8 + xcd;
    if (rowTile >= rtiles) return;

    const __bf16* Atile = A + (size_t)rowTile * ((size_t)K * 128);
    const __bf16* Btile = B + (size_t)colTile * ((size_t)K * 128);

    int tid = threadIdx.x;
    int wave = tid >> 6, lane = tid & 63;
    int wr = wave >> 1, wc = wave & 1;
    int quad = lane >> 4, l16 = lane & 15;

    f32x4 acc[4][4] = {};

    for (int k0 = 0; k0 < K; k0 += 64) {
        __syncthreads();
        const __bf16* gA = Atile + (size_t)k0 * 128;
        const __bf16* gB = Btile + (size_t)k0 * 128;
#pragma unroll
        for (int j = 0; j < 4; ++j) {
            int slot = (j * 256 + tid) * 8;
            load16_lds(gA + slot, Alds + slot);
            load16_lds(gB + slot, Blds + slot);
        }
        __syncthreads();
#pragma unroll
        for (int sp = 0; sp < 2; ++sp) {
            bf16x8 af[4], bf[4];
#pragma unroll
            for (int mi = 0; mi < 4; ++mi)
                af[mi] = *(const bf16x8*)(Alds + sp * 4096 + quad * 1024 +
                                          (wr * 64 + mi * 16 + l16) * 8);
#pragma unroll
            for (int ni = 0; ni < 4; ++ni)
                bf[ni] = *(const bf16x8*)(Blds + sp * 4096 + quad * 1024 +
                                          (wc * 64 + ni * 16 + l16) * 8);
#pragma unroll
            for (int mi = 0; mi < 4; ++mi)
#pragma unroll
                for (int ni = 0; ni < 4; ++ni)
                    acc[mi][ni] = __builtin_amdgcn_mfma_f32_16x16x32_bf16(
                        af[mi], bf[ni], acc[mi][ni], 0, 0, 0);
        }
    }

    int col0 = colTile * 128;
    int row0 = rowTile * 128;
    __syncthreads();

    if (OUTMODE == 0) {
        __bf16* cb = (__bf16*)smem;   // [16 chunks][128 rows][8]
#pragma unroll
        for (int ni = 0; ni < 4; ++ni) {
            int ct = wc * 64 + ni * 16 + l16;
            float bv = bias[col0 + ct];
#pragma unroll
            for (int mi = 0; mi < 4; ++mi) {
                int rb = wr * 64 + mi * 16 + quad * 4;
#pragma unroll
                for (int r = 0; r < 4; ++r) {
                    float v = acc[mi][ni][r] + bv;
                    if (RELU) v = fmaxf(v, 0.f);
                    cb[(ct >> 3) * 1024 + (rb + r) * 8 + (ct & 7)] = (__bf16)v;
                }
            }
        }
        __syncthreads();
        __bf16* dst = osw + (size_t)rowTile * ((size_t)Kc * 128) +
                      (size_t)((coff + col0) >> 3) * 1024;
#pragma unroll
        for (int p2 = 0; p2 < 8; ++p2) {
            int idx = (p2 * 256 + tid) * 8;
            *(uint4*)(dst + idx) = *(const uint4*)(cb + idx);
        }
    } else {
        float* cf = (float*)smem;   // [128][68] fp32, two 64-col halves
#pragma unroll
        for (int h = 0; h < 2; ++h) {
            if (wc == h) {
#pragma unroll
                for (int ni = 0; ni < 4; ++ni) {
                    int ctl = ni * 16 + l16;
                    float bv = bias[col0 + h * 64 + ctl];
#pragma unroll
                    for (int mi = 0; mi < 4; ++mi) {
                        int rb = wr * 64 + mi * 16 + quad * 4;
#pragma unroll
                        for (int r = 0; r < 4; ++r) {
                            float v = acc[mi][ni][r] + bv;
                            if (RELU) v = fmaxf(v, 0.f);
                            cf[(rb + r) * 68 + ctl] = v;
                        }
                    }
                }
            }
            __syncthreads();
            int chunk = tid & 15, rl = tid >> 4;
#pragma unroll
            for (int p2 = 0; p2 < 8; ++p2) {
                int rt = p2 * 16 + rl;
                int row = row0 + rt;
                if (row < M) {
                    float4 v = *(const float4*)(cf + rt * 68 + chunk * 4);
                    *(float4*)(of32 + (size_t)row * ldf + col0 + h * 64 + chunk * 4) = v;
                }
            }
            __syncthreads();
        }
    }
}

// ---------------- launch ----------------

extern "C" void kernel_launch(void* const* d_in, const int* in_sizes, int n_in,
                              void* d_out, int out_size, void* d_ws, size_t ws_size,
                              hipStream_t stream) {
    const float* x   = (const float*)d_in[0];
    const int*   ei  = (const int*)d_in[1];
    const float* Wl1 = (const float*)d_in[2];
    const float* bl1 = (const float*)d_in[3];
    const float* Wr1 = (const float*)d_in[4];
    const float* Wl2 = (const float*)d_in[5];
    const float* bl2 = (const float*)d_in[6];
    const float* Wr2 = (const float*)d_in[7];
    const float* Wl3 = (const float*)d_in[8];
    const float* bl3 = (const float*)d_in[9];
    const float* Wr3 = (const float*)d_in[10];
    const float* Wfc = (const float*)d_in[11];
    const float* bfc = (const float*)d_in[12];
    float* out = (float*)d_out;

    const int NN = N_NODES, E = N_EDGES;
    const int NB = (NN + 1023) / 1024;

    char* p = (char*)d_ws;
    auto alloc = [&](size_t bytes) {
        char* r = p;
        p += (bytes + 511) & ~(size_t)511;
        return r;
    };
    int* cnt   = (int*)alloc((size_t)NN * 4);
    int* off   = (int*)alloc((size_t)(NN + 1) * 4);
    int* cur   = (int*)alloc((size_t)NN * 4);
    int* csr   = (int*)alloc((size_t)E * 4);
    int* bsum  = (int*)alloc((size_t)NB * 4);
    int* carry = (int*)alloc((size_t)NB * 4);
    __bf16* Acat1 = (__bf16*)alloc((size_t)MPAD * 512 * 2);    // swz [mean|x]
    __bf16* Acat2 = (__bf16*)alloc((size_t)MPAD * 1024 * 2);   // swz [mean|h1]
    __bf16* Acat3 = (__bf16*)alloc((size_t)MPAD * 1024 * 2);   // swz [mean|h2]
    __bf16* Wt1 = (__bf16*)alloc((size_t)512 * 512 * 2);
    __bf16* Wt2 = (__bf16*)alloc((size_t)512 * 1024 * 2);
    __bf16* Wt3 = (__bf16*)alloc((size_t)1024 * 1024 * 2);
    __bf16* Wt4 = (__bf16*)alloc((size_t)512 * 1024 * 2);
    __bf16* H3 = Acat2;   // alias: Acat2 dead after GEMM2 reads it

    // CSR build
    hipMemsetAsync(cnt, 0, (size_t)NN * 4, stream);
    k_count<<<(E + 255) / 256, 256, 0, stream>>>(ei, E, cnt);
    k_scan_block<<<NB, 1024, 0, stream>>>(cnt, off, bsum, NN);
    k_scan_carry<<<1, 64, 0, stream>>>(bsum, carry, NB, off, NN);
    k_scan_add<<<NB, 1024, 0, stream>>>(off, cur, carry, NN);
    k_fill<<<(E + 255) / 256, 256, 0, stream>>>(ei, E, cur, csr);

    // fused weight transposes
    TDescs td;
    td.d[0] = {Wl1, Wt1, 256, 512, 512, 0, 0};
    td.d[1] = {Wr1, Wt1, 256, 512, 512, 256, 128};
    td.d[2] = {Wl2, Wt2, 512, 512, 1024, 0, 256};
    td.d[3] = {Wr2, Wt2, 512, 512, 1024, 512, 512};
    td.d[4] = {Wl3, Wt3, 512, 1024, 1024, 0, 768};
    td.d[5] = {Wr3, Wt3, 512, 1024, 1024, 512, 1280};
    td.d[6] = {Wfc, Wt4, 1024, 512, 1024, 0, 1792};
    k_transpose_all<<<2304, dim3(32, 8), 0, stream>>>(td);

    // x -> swizzled bf16 right half of Acat1
    k_convx<<<dim3(157, 16), 256, 0, stream>>>(x, Acat1);

    int rtiles = (NN + 127) / 128;        // 157
    int rg = ((rtiles + 7) / 8) * 8;      // 160

    // Layer 1
    k_agg1<<<313 * 8, 256, 0, stream>>>(off, csr, Acat1);
    k_gemm<true, 0><<<rg * 4, 256, 0, stream>>>(
        Acat1, 512, NN, Wt1, bl1, Acat2, 1024, 512, nullptr, 0, rtiles, 2);

    // Layer 2
    k_agg2<<<625 * 8, 256, 0, stream>>>(Acat2, off, csr, Acat2);
    k_gemm<true, 0><<<rg * 4, 256, 0, stream>>>(
        Acat2, 1024, NN, Wt2, bl2, Acat3, 1024, 512, nullptr, 0, rtiles, 2);

    // Layer 3
    k_agg2<<<625 * 8, 256, 0, stream>>>(Acat3, off, csr, Acat3);
    k_gemm<true, 0><<<rg * 8, 256, 0, stream>>>(
        Acat3, 1024, NN, Wt3, bl3, H3, 1024, 0, nullptr, 0, rtiles, 3);

    // FC (fp32 row-major out, no relu)
    k_gemm<false, 2><<<rg * 4, 256, 0, stream>>>(
        H3, 1024, NN, Wt4, bfc, nullptr, 0, 0, out, 512, rtiles, 2);
}